// Round 2
// baseline (706.247 us; speedup 1.0000x reference)
//
#include <hip/hip_runtime.h>
#include <hip/hip_bf16.h>

typedef unsigned int u32;
typedef unsigned short u16;
typedef unsigned long long u64;
typedef __attribute__((ext_vector_type(8))) short bf16x8;
typedef __attribute__((ext_vector_type(4))) float f32x4;

// Problem constants
#define NWORDS 4096   // B*S
#define CC 32         // chars per word
#define EE 128        // embed dim
#define HHH 256       // hidden
#define MMW 32        // words per block (2 m-tiles per wave)
#define VOCABN 262

// LDS row strides
#define HS 264        // u16 stride for h arrays (proven R15/R18)
#define ES 136        // u16 stride for emb tiles (same 2-way-free bank pattern as HS)

// Workspace layout (u16 units):
//   HH pack per dir: frag[(nt*3+g)*8+kc][lane][8] -> 16*3*8*512 u16 (bf16 hi of Whh)
//   IH pack per dir: frag[(nt*3+g)*4+kc][lane][8] -> 16*3*4*512 u16 (bf16 hi of Wih)
//   EMB pack: [262][256] u16 = per char row: [0..127]=bf16 hi, [128..255]=bf16 lo
//   bias per dir 1024 f32: [0..511]=bih+bhh(r,z); [512..767]=bih_n; [768..1023]=bhh_n
#define PK_HHD (16*3*8*512)                   // 196608
#define PK_IHD (16*3*4*512)                   // 98304
#define IH_OFF_U16 (2*PK_HHD)                 // 393216
#define EMB_OFF_U16 (IH_OFF_U16 + 2*PK_IHD)   // 589824
#define EMBD 256
#define BIAS_OFF_U16 (EMB_OFF_U16 + VOCABN*EMBD)  // 656896 (byte 1313792, 4-aligned)

// fused-prep grid split
#define PREP_PACK_BLKS ((2*PK_HHD + 2*PK_IHD)/256)     // 2304
#define PREP_EMB_BLKS VOCABN                           // 262
#define PREP_BLKS (PREP_PACK_BLKS + PREP_EMB_BLKS + 1) // 2567

__device__ __forceinline__ float bf2f(u16 u){ union{u32 i; float f;} v; v.i=((u32)u)<<16; return v.f; }
__device__ __forceinline__ u16 f2bf(float f){
  __hip_bfloat16 h = __float2bfloat16(f);   // rne
  u16 r; __builtin_memcpy(&r, &h, 2); return r;
}
__device__ __forceinline__ float sigmoid_f(float x){
  float e = __builtin_amdgcn_exp2f(-1.4426950408889634f * x);
  return __builtin_amdgcn_rcpf(1.0f + e);
}
__device__ __forceinline__ float tanh_f(float x){
  float ax = __builtin_fabsf(x);
  float e  = __builtin_amdgcn_exp2f(-2.8853900817779268f * ax);
  float t  = 1.0f - 2.0f * e * __builtin_amdgcn_rcpf(1.0f + e);
  return __builtin_copysignf(t, x);
}

// ---- fused prep: Whh+Wih packs + emb hi/lo pack + biases, one launch ----
__global__ void prep_all(const float* __restrict__ emb,
                         const float* __restrict__ Wih_fw, const float* __restrict__ Whh_fw,
                         const float* __restrict__ bih_fw, const float* __restrict__ bhh_fw,
                         const float* __restrict__ Wih_bw, const float* __restrict__ Whh_bw,
                         const float* __restrict__ bih_bw, const float* __restrict__ bhh_bw,
                         u16* __restrict__ wsu)
{
  const int bid = blockIdx.x, tid = threadIdx.x;
  if (bid < PREP_PACK_BLKS) {
    int idx = bid*256 + tid;
    if (idx < 2*PK_HHD) {
      // -------- Whh pack (bf16 hi only), kc<8 --------
      int d = idx / PK_HHD;
      int e = idx - d*PK_HHD;
      const float* Whh = d ? Whh_bw : Whh_fw;
      int jj   = e & 7;
      int lane = (e >> 3) & 63;
      int kc   = (e >> 9) & 7;
      int gnt  = e >> 12;                     // nt*3+g, < 48
      int g = gnt % 3, nt = gnt / 3;
      int row = g*256 + nt*16 + (lane & 15);
      int k   = kc*32 + ((lane >> 4) << 3) + jj;
      wsu[idx] = f2bf(Whh[row*HHH + k]);
    } else {
      // -------- Wih pack (bf16 hi only), kc<4, k-dim = EE --------
      int e2 = idx - 2*PK_HHD;
      int d = e2 / PK_IHD;
      int e = e2 - d*PK_IHD;
      const float* Wih = d ? Wih_bw : Wih_fw;
      int jj   = e & 7;
      int lane = (e >> 3) & 63;
      int kc   = (e >> 9) & 3;
      int gnt  = e >> 11;                     // nt*3+g, < 48
      int g = gnt % 3, nt = gnt / 3;
      int row = g*256 + nt*16 + (lane & 15);
      int k   = kc*32 + ((lane >> 4) << 3) + jj;
      wsu[idx] = f2bf(Wih[row*EE + k]);
    }
  } else if (bid < PREP_PACK_BLKS + PREP_EMB_BLKS) {
    // -------- emb hi/lo pack: one block per vocab char --------
    int c = bid - PREP_PACK_BLKS;
    int t2 = tid & 127;
    float f = emb[(size_t)c*EE + t2];
    u16 hi = f2bf(f);
    u16 v = (tid < 128) ? hi : f2bf(f - bf2f(hi));
    wsu[EMB_OFF_U16 + c*EMBD + tid] = v;      // [0..127]=hi, [128..255]=lo
  } else {
    // -------- biases (one block handles all 2048, 8 per thread) --------
    #pragma unroll
    for (int rep = 0; rep < 8; ++rep) {
      int i = rep*256 + tid;
      int d = i >> 10, o = i & 1023;
      const float* bih = d ? bih_bw : bih_fw;
      const float* bhh = d ? bhh_bw : bhh_fw;
      float v;
      if (o < 512)      v = bih[o] + bhh[o];
      else if (o < 768) v = bih[o - 512 + 512];   // bih_n
      else              v = bhh[o - 768 + 512];   // bhh_n
      ((float*)(wsu + BIAS_OFF_U16))[d*1024 + o] = v;
    }
  }
}

// ==== R18 2-barrier skeleton; XP table replaced by on-the-fly xp-GEMM:
//  per step, xp = emb[ci] @ Wih^T computed with MFMA (emb hi for r,z; hi+lo for n).
//  emb rows (random, 134 KB table -> L2-hot) staged into double-buffered LDS:
//  global load issued pre-S0, ds_write after xp phase (T14 split); ping-pong
//  buffers mean no extra barrier (write target != read target, S2+S0 between).
//  Wih frags (192 B/lane/step) stream lockstep from L2 like Whh.
//  h/mask/output epilogue fully registerized (R1, verified).
__global__ __launch_bounds__(1024)
void gru_mfma(const int* __restrict__ chars, const int* __restrict__ chars_mask,
              const int* __restrict__ data_mask, const u16* __restrict__ wsu,
              float* __restrict__ out)
{
  const int dir   = blockIdx.x & 1;           // XCD parity: one dir per XCD
  const int word0 = (blockIdx.x >> 1) * MMW;
  const int j     = threadIdx.x;              // 0..1023 = 16 waves (4 per SIMD)
  const int wave  = j >> 6, lane = j & 63;
  const int quad  = lane >> 4, l15 = lane & 15;

  const bf16x8* pHH  = (const bf16x8*)(wsu + (size_t)dir*PK_HHD);
  const bf16x8* bIH  = (const bf16x8*)(wsu + IH_OFF_U16 + (size_t)dir*PK_IHD)
                       + (size_t)(wave*3)*4*64 + lane;
  const u16*    embp = wsu + EMB_OFF_U16;
  const float*  bias = (const float*)(wsu + BIAS_OFF_U16) + dir*1024;

  // this wave owns gate-tile nt == wave (16 output channels)
  const bf16x8* bHH = pHH + (size_t)(wave*3)*8*64 + lane;

  __shared__ __align__(16) u16 sh_hhi[MMW][HS];     // bf16 hi of h (16.9 KB)
  __shared__ __align__(16) u16 sh_hlo[MMW][HS];     // bf16 lo of h (16.9 KB)
  __shared__ __align__(16) u16 sh_ehi[2][MMW][ES];  // emb hi, dbuf (17.4 KB)
  __shared__ __align__(16) u16 sh_elo[2][MMW][ES];  // emb lo, dbuf (17.4 KB)
  __shared__ __align__(16) int sh_cit[CC][MMW];     // chars, transposed (4 KB)
  __shared__ u32 sh_mb[MMW];                        // per-word step-mask bits

  const int sw2 = j >> 5, pp = j & 31;        // staging: word (32), uint4 part (32)

  // ---- one-time staging ----
  {
    const int w = sw2, c = pp;
    sh_cit[c][w] = chars[(word0 + w)*CC + c];
    int mv = chars_mask[(word0 + w)*CC + c];
    u64 bal = __ballot(mv != 0);              // lanes 0..31 -> word 2*wave, 32..63 -> 2*wave+1
    if (lane == 0) {
      sh_mb[2*wave]     = (u32)bal;
      sh_mb[2*wave + 1] = (u32)(bal >> 32);
    }
  }
  for (int i = j; i < MMW*HS/2; i += 1024) { ((float*)sh_hhi)[i] = 0.0f; ((float*)sh_hlo)[i] = 0.0f; }
  // stage emb buf0 for first char (read chars directly: sh_cit not yet visible)
  {
    int t0 = dir ? (CC - 1) : 0;
    int ci0 = chars[(word0 + sw2)*CC + t0];
    uint4 ev0 = *(const uint4*)(embp + (size_t)ci0*EMBD + pp*8);
    if (pp < 16) *(uint4*)&sh_ehi[0][sw2][pp*8]      = ev0;
    else         *(uint4*)&sh_elo[0][sw2][(pp-16)*8] = ev0;
  }
  __syncthreads();

  const int ch = wave*16 + l15;               // this lane's output channel
  const float bR  = bias[ch],        bZ  = bias[256 + ch];
  const float bXN = bias[512 + ch],  bHN = bias[768 + ch];

  // per-lane owned words: word = m*16 + quad*4 + r
  u32 mb[2][4];
  float hreg[2][4];
  #pragma unroll
  for (int m = 0; m < 2; ++m)
    #pragma unroll
    for (int r = 0; r < 4; ++r) {
      mb[m][r] = sh_mb[m*16 + quad*4 + r];
      hreg[m][r] = 0.0f;
    }

  // 8 HH batches per step (kc 0..7), 3 frags each; 4-slot rotation (proven R18)
  bf16x8 buf[4][3];
  auto load_batch = [&](int kc, bf16x8 dst[3]) {
    #pragma unroll
    for (int g = 0; g < 3; ++g) dst[g] = bHH[(g*8 + kc)*64];
  };
  load_batch(0, buf[0]);
  load_batch(1, buf[1]);
  load_batch(2, buf[2]);

  #pragma unroll 1
  for (int s = 0; s < CC; ++s) {
    // ---- pre-issue next step's emb row load (consumed after xp phase) ----
    uint4 ev;
    const bool hasn = (s + 1 < CC);
    if (hasn) {
      int tn = dir ? (CC - 2 - s) : (s + 1);
      int ci = sh_cit[tn][sw2];
      ev = *(const uint4*)(embp + (size_t)ci*EMBD + pp*8);
    }

    __syncthreads();                                   // S0: h + emb writes visible

    // acc[0]=r, acc[1]=z, acc[2]=hn, acc[3]=xn ; [m-tile]  (32 regs)
    f32x4 acc[4][2];
    #pragma unroll
    for (int m = 0; m < 2; ++m) {
      acc[0][m] = (f32x4){bR,bR,bR,bR};
      acc[1][m] = (f32x4){bZ,bZ,bZ,bZ};
      acc[2][m] = (f32x4){bHN,bHN,bHN,bHN};
      acc[3][m] = (f32x4){bXN,bXN,bXN,bXN};
    }

    // ---- xp-GEMM: emb(hi;hi+lo for n) x Wih -> r,z,xn (32 MFMA/wave) ----
    const int eb = s & 1;
    #pragma unroll
    for (int kc = 0; kc < 4; ++kc) {
      bf16x8 wr = bIH[kc*64];
      bf16x8 wz = bIH[(4 + kc)*64];
      bf16x8 wn = bIH[(8 + kc)*64];
      #pragma unroll
      for (int m = 0; m < 2; ++m) {
        bf16x8 eh = *(const bf16x8*)&sh_ehi[eb][m*16 + l15][kc*32 + quad*8];
        bf16x8 el = *(const bf16x8*)&sh_elo[eb][m*16 + l15][kc*32 + quad*8];
        acc[0][m] = __builtin_amdgcn_mfma_f32_16x16x32_bf16(eh, wr, acc[0][m], 0,0,0);
        acc[1][m] = __builtin_amdgcn_mfma_f32_16x16x32_bf16(eh, wz, acc[1][m], 0,0,0);
        acc[3][m] = __builtin_amdgcn_mfma_f32_16x16x32_bf16(eh, wn, acc[3][m], 0,0,0);
        acc[3][m] = __builtin_amdgcn_mfma_f32_16x16x32_bf16(el, wn, acc[3][m], 0,0,0);
      }
    }

    // ---- write next emb tile into the other buffer (T14 late-write) ----
    if (hasn) {
      if (pp < 16) *(uint4*)&sh_ehi[eb^1][sw2][pp*8]      = ev;
      else         *(uint4*)&sh_elo[eb^1][sw2][(pp-16)*8] = ev;
    }

    // ---- h-GEMM: r,z from h_hi; n exact hi+lo (64 MFMA/wave) ----
    auto mfma_batch = [&](int kc, bf16x8 src[3]) {
      #pragma unroll
      for (int m = 0; m < 2; ++m) {
        bf16x8 ah = *(const bf16x8*)&sh_hhi[m*16 + l15][kc*32 + quad*8];
        bf16x8 al = *(const bf16x8*)&sh_hlo[m*16 + l15][kc*32 + quad*8];
        acc[0][m] = __builtin_amdgcn_mfma_f32_16x16x32_bf16(ah, src[0], acc[0][m], 0,0,0);
        acc[1][m] = __builtin_amdgcn_mfma_f32_16x16x32_bf16(ah, src[1], acc[1][m], 0,0,0);
        acc[2][m] = __builtin_amdgcn_mfma_f32_16x16x32_bf16(ah, src[2], acc[2][m], 0,0,0);
        acc[2][m] = __builtin_amdgcn_mfma_f32_16x16x32_bf16(al, src[2], acc[2][m], 0,0,0);
      }
    };

    #pragma unroll
    for (int b = 0; b < 8; ++b) {
      mfma_batch(b, buf[b & 3]);
      load_batch((b + 3) & 7, buf[(b + 3) & 3]);       // b>=5 pre-issues next step's 0,1,2
    }

    __syncthreads();                                   // S2: frag reads + emb writes done

    // ---- gate math + h update (lane owns (word, ch); h_old in regs) ----
    const int t = dir ? (CC - 1 - s) : s;
    #pragma unroll
    for (int m = 0; m < 2; ++m)
      #pragma unroll
      for (int r = 0; r < 4; ++r) {
        const int word = m*16 + quad*4 + r;
        float rr = sigmoid_f(acc[0][m][r]);
        float zz = sigmoid_f(acc[1][m][r]);
        float nn = tanh_f(fmaf(rr, acc[2][m][r], acc[3][m][r]));
        float hold = hreg[m][r];
        float hnew = fmaf(zz, hold - nn, nn);                  // (1-z)*n + z*h
        float cmf  = (float)((mb[m][r] >> t) & 1u);
        float hm   = fmaf(cmf, hnew - hold, hold);             // mask freeze
        hreg[m][r] = hm;
        u16 hi = f2bf(hm);
        sh_hhi[word][ch] = hi;
        sh_hlo[word][ch] = f2bf(hm - bf2f(hi));
      }
  }

  // ---- output straight from registers (owner mapping) ----
  #pragma unroll
  for (int m = 0; m < 2; ++m)
    #pragma unroll
    for (int r = 0; r < 4; ++r) {
      const int word = m*16 + quad*4 + r;
      float dm = (float)data_mask[word0 + word];
      out[(size_t)(word0 + word)*(2*HHH) + dir*HHH + ch] = hreg[m][r] * dm;
    }
}

extern "C" void kernel_launch(void* const* d_in, const int* in_sizes, int n_in,
                              void* d_out, int out_size, void* d_ws, size_t ws_size,
                              hipStream_t stream) {
  const int*   chars      = (const int*)d_in[0];
  const int*   chars_mask = (const int*)d_in[1];
  const int*   data_mask  = (const int*)d_in[2];
  const float* embed      = (const float*)d_in[3];
  const float* Wih_fw     = (const float*)d_in[4];
  const float* Whh_fw     = (const float*)d_in[5];
  const float* bih_fw     = (const float*)d_in[6];
  const float* bhh_fw     = (const float*)d_in[7];
  const float* Wih_bw     = (const float*)d_in[8];
  const float* Whh_bw     = (const float*)d_in[9];
  const float* bih_bw     = (const float*)d_in[10];
  const float* bhh_bw     = (const float*)d_in[11];
  u16* wsu = (u16*)d_ws;

  prep_all<<<PREP_BLKS, 256, 0, stream>>>(embed, Wih_fw, Whh_fw, bih_fw, bhh_fw,
                                          Wih_bw, Whh_bw, bih_bw, bhh_bw, wsu);

  // 256 blocks: (word-group, dir) packed so dir == blockIdx&1 (XCD parity)
  gru_mfma<<<(NWORDS/MMW)*2, 1024, 0, stream>>>(chars, chars_mask, data_mask, wsu, (float*)d_out);
}

// Round 3
// 608.913 us; speedup vs baseline: 1.1598x; 1.1598x over previous
//
#include <hip/hip_runtime.h>
#include <hip/hip_bf16.h>

typedef unsigned int u32;
typedef unsigned short u16;
typedef unsigned long long u64;
typedef __attribute__((ext_vector_type(8))) short bf16x8;
typedef __attribute__((ext_vector_type(4))) float f32x4;

// Problem constants
#define NWORDS 4096   // B*S
#define CC 32         // chars per word
#define EE 128        // embed dim
#define HHH 256       // hidden
#define MMW 32        // words per block (2 m-tiles per wave)
#define VOCABN 262

// LDS row strides
#define HS 264        // u16 stride for h arrays (fastest measured, R15/R18)
#define XPS 784       // u16 stride for xp rows (392 dw)

// Workspace layout (u16 units):
//   HH pack per dir: frag[(nt*3+g)*8+kc][lane][8] -> 16*3*8*512 = 196608 u16 (bf16 hi of Whh)
//   XP table per dir: [262][768] bf16 = embed @ Wih^T (no bias)
//   bias: per dir 1024 f32: [0..511]=bih+bhh(r,z); [512..767]=bih_n; [768..1023]=bhh_n
#define PK_HHD (16*3*8*512)                  // 196608
#define XP_OFF_U16 (2*PK_HHD)                // 393216
#define XPD (VOCABN*768)                     // 201216
#define BIAS_OFF_U16 (XP_OFF_U16 + 2*XPD)    // 795648 (byte 1591296, 4-aligned)

// fused-prep grid split
#define XP_NCH 8
#define XP_CBLK ((VOCABN + XP_NCH - 1) / XP_NCH)      // 33
#define PREP_PACK_BLKS (2*PK_HHD/256)                 // 1536
#define PREP_XP_BLKS (XP_CBLK*2)                      // 66
#define PREP_BLKS (PREP_PACK_BLKS + PREP_XP_BLKS + 1) // 1603

__device__ __forceinline__ float bf2f(u16 u){ union{u32 i; float f;} v; v.i=((u32)u)<<16; return v.f; }
__device__ __forceinline__ u16 f2bf(float f){
  __hip_bfloat16 h = __float2bfloat16(f);   // rne
  u16 r; __builtin_memcpy(&r, &h, 2); return r;
}
__device__ __forceinline__ float sigmoid_f(float x){
  float e = __builtin_amdgcn_exp2f(-1.4426950408889634f * x);
  return __builtin_amdgcn_rcpf(1.0f + e);
}
__device__ __forceinline__ float tanh_f(float x){
  float ax = __builtin_fabsf(x);
  float e  = __builtin_amdgcn_exp2f(-2.8853900817779268f * ax);
  float t  = 1.0f - 2.0f * e * __builtin_amdgcn_rcpf(1.0f + e);
  return __builtin_copysignf(t, x);
}

// ---- fused prep: Whh pack + tiled XP table + biases, one launch (R15) ----
__global__ void prep_all(const float* __restrict__ emb,
                         const float* __restrict__ Wih_fw, const float* __restrict__ Whh_fw,
                         const float* __restrict__ bih_fw, const float* __restrict__ bhh_fw,
                         const float* __restrict__ Wih_bw, const float* __restrict__ Whh_bw,
                         const float* __restrict__ bih_bw, const float* __restrict__ bhh_bw,
                         u16* __restrict__ wsu)
{
  const int bid = blockIdx.x, tid = threadIdx.x;
  if (bid < PREP_PACK_BLKS) {
    // -------- Whh pack (bf16 hi only) --------
    int idx = bid*256 + tid;                  // 2*PK_HHD elements
    int d = idx / PK_HHD;
    int e = idx - d*PK_HHD;
    const float* Whh = d ? Whh_bw : Whh_fw;
    int jj   = e & 7;
    int lane = (e >> 3) & 63;
    int kc   = (e >> 9) & 7;
    int gnt  = e >> 12;                       // nt*3+g, < 48
    int g = gnt % 3, nt = gnt / 3;
    int row = g*256 + nt*16 + (lane & 15);
    int k   = kc*32 + ((lane >> 4) << 3) + jj;
    wsu[idx] = f2bf(Whh[row*HHH + k]);
  } else if (bid < PREP_PACK_BLKS + PREP_XP_BLKS) {
    // -------- XP table, tiled: block = (8 chars x dir), embed rows in LDS --------
    const int b    = bid - PREP_PACK_BLKS;
    const int dirb = b & 1;
    const int c0   = (b >> 1) * XP_NCH;
    const float* Wih = dirb ? Wih_bw : Wih_fw;
    u16* xpo = wsu + XP_OFF_U16 + (size_t)dirb*XPD;

    __shared__ float sh_E[XP_NCH][EE];        // 4 KB
    for (int i = tid; i < XP_NCH*EE; i += 256) {
      int c = c0 + i/EE;
      sh_E[0][i] = (c < VOCABN) ? emb[(size_t)c*EE + (i & (EE-1))] : 0.0f;
    }
    __syncthreads();

    #pragma unroll 1
    for (int q = 0; q < 3; ++q) {             // gate channel g = q*256 + tid
      const int g = q*256 + tid;
      const float* W = Wih + (size_t)g*EE;
      float acc[XP_NCH];
      #pragma unroll
      for (int c = 0; c < XP_NCH; ++c) acc[c] = 0.0f;
      #pragma unroll 2
      for (int k = 0; k < EE; k += 4) {
        float4 wv = *(const float4*)(W + k);
        #pragma unroll
        for (int c = 0; c < XP_NCH; ++c) {
          float4 ev = *(const float4*)(&sh_E[c][k]);
          acc[c] = fmaf(ev.w, wv.w, fmaf(ev.z, wv.z, fmaf(ev.y, wv.y, fmaf(ev.x, wv.x, acc[c]))));
        }
      }
      #pragma unroll
      for (int c = 0; c < XP_NCH; ++c) {
        int ci = c0 + c;
        if (ci < VOCABN) xpo[(size_t)ci*768 + g] = f2bf(acc[c]);
      }
    }
  } else {
    // -------- biases (one block handles all 2048, 8 per thread) --------
    #pragma unroll
    for (int rep = 0; rep < 8; ++rep) {
      int i = rep*256 + tid;
      int d = i >> 10, o = i & 1023;
      const float* bih = d ? bih_bw : bih_fw;
      const float* bhh = d ? bhh_bw : bhh_fw;
      float v;
      if (o < 512)      v = bih[o] + bhh[o];
      else if (o < 768) v = bih[o - 512 + 512];   // bih_n
      else              v = bhh[o - 768 + 512];   // bhh_n
      ((float*)(wsu + BIAS_OFF_U16))[d*1024 + o] = v;
    }
  }
}

// ==== R0 (295us) skeleton: XP table + cooperative uint4 row staging into LDS.
// This round's deltas vs R0:
//  - sh_xp double-buffered: loads for step s+1 issued right after S0(s), held in
//    VGPRs across the MFMA phase, ds_write after S2(s) (T14 split) -> the L2/L3
//    miss latency hides under ~6k cycles of MFMA instead of serializing per step.
//  - L2 pollution control: nontemporal stores for out, nontemporal loads for
//    chars/chars_mask/data_mask (all single-touch) -> protect xp-table residency.
//  - R1's verified register diet: h kept in hreg (lane owns (word,ch) forever),
//    chars_mask as per-word 32-bit step masks (ballot), chars transposed for
//    broadcast reads; output written from registers.
__global__ __launch_bounds__(1024)
void gru_mfma(const int* __restrict__ chars, const int* __restrict__ chars_mask,
              const int* __restrict__ data_mask, const u16* __restrict__ wsu,
              float* __restrict__ out)
{
  const int dir   = blockIdx.x & 1;           // XCD parity: one dir per XCD
  const int word0 = (blockIdx.x >> 1) * MMW;
  const int j     = threadIdx.x;              // 0..1023 = 16 waves (4 per SIMD)
  const int wave  = j >> 6, lane = j & 63;
  const int quad  = lane >> 4, l15 = lane & 15;

  const bf16x8* pHH  = (const bf16x8*)(wsu + (size_t)dir*PK_HHD);
  const u16*    xpt  = wsu + XP_OFF_U16 + (size_t)dir*XPD;
  const float*  bias = (const float*)(wsu + BIAS_OFF_U16) + dir*1024;

  // this wave owns gate-tile nt == wave (16 output channels)
  const bf16x8* bHH = pHH + (size_t)(wave*3)*8*64 + lane;

  __shared__ __align__(16) u16 sh_hhi[MMW][HS];      // bf16 hi of h (16.9 KB)
  __shared__ __align__(16) u16 sh_hlo[MMW][HS];      // bf16 lo of h (16.9 KB)
  __shared__ __align__(16) u16 sh_xp[2][MMW][XPS];   // xp rows, dbuf (100.4 KB)
  __shared__ __align__(16) int sh_cit[CC][MMW];      // chars, transposed (4 KB)
  __shared__ u32 sh_mb[MMW];                         // per-word step-mask bits

  const int sw = j >> 5, sp = j & 31;       // xp-staging: word (32), 24-u16 part (32)

  // ---- one-time staging ----
  {
    const int w = sw, c = sp;
    sh_cit[c][w] = __builtin_nontemporal_load(&chars[(word0 + w)*CC + c]);
    int mv = __builtin_nontemporal_load(&chars_mask[(word0 + w)*CC + c]);
    u64 bal = __ballot(mv != 0);            // lanes 0..31 -> word 2*wave, 32..63 -> 2*wave+1
    if (lane == 0) {
      sh_mb[2*wave]     = (u32)bal;
      sh_mb[2*wave + 1] = (u32)(bal >> 32);
    }
  }
  for (int i = j; i < MMW*HS/2; i += 1024) { ((float*)sh_hhi)[i] = 0.0f; ((float*)sh_hlo)[i] = 0.0f; }
  // prologue: stage xp buf0 for the first char (chars read directly; sh_cit not synced yet)
  {
    const int t0 = dir ? (CC - 1) : 0;
    int ci0 = __builtin_nontemporal_load(&chars[(word0 + sw)*CC + t0]);
    const uint4* src = (const uint4*)(xpt + (size_t)ci0*768);   // 96 uint4 per row
    uint4 a0 = src[sp*3], a1 = src[sp*3+1], a2 = src[sp*3+2];
    *(uint4*)&sh_xp[0][sw][sp*24]      = a0;
    *(uint4*)&sh_xp[0][sw][sp*24 + 8]  = a1;
    *(uint4*)&sh_xp[0][sw][sp*24 + 16] = a2;
  }
  __syncthreads();

  const int ch = wave*16 + l15;             // this lane's output channel
  const float bR  = bias[ch],        bZ  = bias[256 + ch];
  const float bXN = bias[512 + ch],  bHN = bias[768 + ch];

  // per-lane owned words: word = m*16 + quad*4 + r
  u32 mb[2][4];
  float hreg[2][4];
  #pragma unroll
  for (int m = 0; m < 2; ++m)
    #pragma unroll
    for (int r = 0; r < 4; ++r) {
      mb[m][r] = sh_mb[m*16 + quad*4 + r];
      hreg[m][r] = 0.0f;
    }

  // 8 HH batches per step (kc 0..7), 3 frags each. FOUR buffer slots so the
  // rotation is step-aligned (8 % 4 == 0; 3 slots permuted kc across steps).
  bf16x8 buf[4][3];
  auto load_batch = [&](int kc, bf16x8 dst[3]) {
    #pragma unroll
    for (int g = 0; g < 3; ++g) dst[g] = bHH[(g*8 + kc)*64];
  };
  load_batch(0, buf[0]);
  load_batch(1, buf[1]);
  load_batch(2, buf[2]);

  #pragma unroll 1
  for (int s = 0; s < CC; ++s) {
    __syncthreads();                                   // S0: h writes visible

    // ---- issue next step's xp row loads (drain at ds_write after S2) ----
    uint4 a0, a1, a2;
    const bool hasn = (s + 1 < CC);
    if (hasn) {
      int tn = dir ? (CC - 2 - s) : (s + 1);
      int ci = sh_cit[tn][sw];
      const uint4* src = (const uint4*)(xpt + (size_t)ci*768);
      a0 = src[sp*3]; a1 = src[sp*3+1]; a2 = src[sp*3+2];
    }

    // acc[0]=r, acc[1]=z, acc[2]=hn ; [m-tile]  (24 regs)
    f32x4 acc[3][2];
    #pragma unroll
    for (int m = 0; m < 2; ++m) {
      acc[0][m] = (f32x4){bR,bR,bR,bR};
      acc[1][m] = (f32x4){bZ,bZ,bZ,bZ};
      acc[2][m] = (f32x4){bHN,bHN,bHN,bHN};
    }

    // r,z gates: h_hi only (bounded, non-compounding error). n gate: exact hi+lo.
    auto mfma_batch = [&](int kc, bf16x8 src[3]) {
      #pragma unroll
      for (int m = 0; m < 2; ++m) {
        bf16x8 ah = *(const bf16x8*)&sh_hhi[m*16 + l15][kc*32 + quad*8];
        bf16x8 al = *(const bf16x8*)&sh_hlo[m*16 + l15][kc*32 + quad*8];
        acc[0][m] = __builtin_amdgcn_mfma_f32_16x16x32_bf16(ah, src[0], acc[0][m], 0,0,0);
        acc[1][m] = __builtin_amdgcn_mfma_f32_16x16x32_bf16(ah, src[1], acc[1][m], 0,0,0);
        acc[2][m] = __builtin_amdgcn_mfma_f32_16x16x32_bf16(ah, src[2], acc[2][m], 0,0,0);
        acc[2][m] = __builtin_amdgcn_mfma_f32_16x16x32_bf16(al, src[2], acc[2][m], 0,0,0);
      }
    };

    #pragma unroll
    for (int b = 0; b < 8; ++b) {
      mfma_batch(b, buf[b & 3]);
      load_batch((b + 3) & 7, buf[(b + 3) & 3]);       // b>=5 pre-issues next step's 0,1,2
    }

    __syncthreads();                                   // S2: h frag + prev xp reads done

    // ---- write next step's xp rows into the other buffer (T14 late-write) ----
    if (hasn) {
      *(uint4*)&sh_xp[(s+1)&1][sw][sp*24]      = a0;
      *(uint4*)&sh_xp[(s+1)&1][sw][sp*24 + 8]  = a1;
      *(uint4*)&sh_xp[(s+1)&1][sw][sp*24 + 16] = a2;
    }

    // ---- gate math + h update (lane owns (word, ch); h_old in regs) ----
    const int t = dir ? (CC - 1 - s) : s;
    const u16* xrow0 = &sh_xp[s & 1][0][0];
    #pragma unroll
    for (int m = 0; m < 2; ++m)
      #pragma unroll
      for (int r = 0; r < 4; ++r) {
        const int word = m*16 + quad*4 + r;
        const u16* xrow = xrow0 + (size_t)word*XPS;
        float xr = bf2f(xrow[ch]);
        float xz = bf2f(xrow[256 + ch]);
        float xn = bf2f(xrow[512 + ch]);
        float rr = sigmoid_f(acc[0][m][r] + xr);
        float zz = sigmoid_f(acc[1][m][r] + xz);
        float nn = tanh_f(fmaf(rr, acc[2][m][r], bXN + xn));
        float hold = hreg[m][r];
        float hnew = fmaf(zz, hold - nn, nn);                  // (1-z)*n + z*h
        float cmf  = (float)((mb[m][r] >> t) & 1u);
        float hm   = fmaf(cmf, hnew - hold, hold);             // mask freeze
        hreg[m][r] = hm;
        u16 hi = f2bf(hm);
        sh_hhi[word][ch] = hi;
        sh_hlo[word][ch] = f2bf(hm - bf2f(hi));
      }
  }

  // ---- output straight from registers (owner mapping), nt stores ----
  #pragma unroll
  for (int m = 0; m < 2; ++m)
    #pragma unroll
    for (int r = 0; r < 4; ++r) {
      const int word = m*16 + quad*4 + r;
      float dm = (float)__builtin_nontemporal_load(&data_mask[word0 + word]);
      __builtin_nontemporal_store(hreg[m][r] * dm,
                                  &out[(size_t)(word0 + word)*(2*HHH) + dir*HHH + ch]);
    }
}

extern "C" void kernel_launch(void* const* d_in, const int* in_sizes, int n_in,
                              void* d_out, int out_size, void* d_ws, size_t ws_size,
                              hipStream_t stream) {
  const int*   chars      = (const int*)d_in[0];
  const int*   chars_mask = (const int*)d_in[1];
  const int*   data_mask  = (const int*)d_in[2];
  const float* embed      = (const float*)d_in[3];
  const float* Wih_fw     = (const float*)d_in[4];
  const float* Whh_fw     = (const float*)d_in[5];
  const float* bih_fw     = (const float*)d_in[6];
  const float* bhh_fw     = (const float*)d_in[7];
  const float* Wih_bw     = (const float*)d_in[8];
  const float* Whh_bw     = (const float*)d_in[9];
  const float* bih_bw     = (const float*)d_in[10];
  const float* bhh_bw     = (const float*)d_in[11];
  u16* wsu = (u16*)d_ws;

  prep_all<<<PREP_BLKS, 256, 0, stream>>>(embed, Wih_fw, Whh_fw, bih_fw, bhh_fw,
                                          Wih_bw, Whh_bw, bih_bw, bhh_bw, wsu);

  // 256 blocks: (word-group, dir) packed so dir == blockIdx&1 (XCD parity)
  gru_mfma<<<(NWORDS/MMW)*2, 1024, 0, stream>>>(chars, chars_mask, data_mask, wsu, (float*)d_out);
}

// Round 4
// 402.317 us; speedup vs baseline: 1.7554x; 1.5135x over previous
//
#include <hip/hip_runtime.h>
#include <hip/hip_bf16.h>

typedef unsigned int u32;
typedef unsigned short u16;
typedef unsigned long long u64;
typedef __attribute__((ext_vector_type(8))) short bf16x8;
typedef __attribute__((ext_vector_type(4))) float f32x4;

// Problem constants
#define NWORDS 4096   // B*S
#define CC 32         // chars per word
#define EE 128        // embed dim
#define HHH 256       // hidden
#define MMW 32        // words per block (2 m-tiles per wave)
#define VOCABN 262

// LDS strides
#define HS 264        // u16 stride for h arrays (fastest measured, R15/R18)
#define XPW 528       // u16 stride per wave-pair row in xp planes (1056 B; %128dw=8 -> 2-way-free reads)
#define XPL (16*XPW)  // u16 stride per gate plane (8448)

// Workspace layout (u16 units):
//   HH pack per dir: frag[(nt*3+g)*8+kc][lane][8] -> 16*3*8*512 = 196608 u16 (bf16 hi of Whh)
//   XP table per dir: [262][768] bf16 = embed @ Wih^T (no bias), gate-major per row
//   bias: per dir 1024 f32: [0..511]=bih+bhh(r,z); [512..767]=bih_n; [768..1023]=bhh_n
#define PK_HHD (16*3*8*512)                  // 196608
#define XP_OFF_U16 (2*PK_HHD)                // 393216
#define XPD (VOCABN*768)                     // 201216
#define BIAS_OFF_U16 (XP_OFF_U16 + 2*XPD)    // 795648 (byte 1591296, 4-aligned)

// fused-prep grid split
#define XP_NCH 8
#define XP_CBLK ((VOCABN + XP_NCH - 1) / XP_NCH)      // 33
#define PREP_PACK_BLKS (2*PK_HHD/256)                 // 1536
#define PREP_XP_BLKS (XP_CBLK*2)                      // 66
#define PREP_BLKS (PREP_PACK_BLKS + PREP_XP_BLKS + 1) // 1603

__device__ __forceinline__ float bf2f(u16 u){ union{u32 i; float f;} v; v.i=((u32)u)<<16; return v.f; }
__device__ __forceinline__ u16 f2bf(float f){
  __hip_bfloat16 h = __float2bfloat16(f);   // rne
  u16 r; __builtin_memcpy(&r, &h, 2); return r;
}
__device__ __forceinline__ float sigmoid_f(float x){
  float e = __builtin_amdgcn_exp2f(-1.4426950408889634f * x);
  return __builtin_amdgcn_rcpf(1.0f + e);
}
__device__ __forceinline__ float tanh_f(float x){
  float ax = __builtin_fabsf(x);
  float e  = __builtin_amdgcn_exp2f(-2.8853900817779268f * ax);
  float t  = 1.0f - 2.0f * e * __builtin_amdgcn_rcpf(1.0f + e);
  return __builtin_copysignf(t, x);
}
// async global->LDS, 16B per lane, dest = uniform base + lane*16
__device__ __forceinline__ void gload_lds16(const void* g, void* l) {
  __builtin_amdgcn_global_load_lds((const __attribute__((address_space(1))) void*)g,
                                   (__attribute__((address_space(3))) void*)l, 16, 0, 0);
}

// ---- fused prep: Whh pack + tiled XP table + biases, one launch (R15) ----
__global__ void prep_all(const float* __restrict__ emb,
                         const float* __restrict__ Wih_fw, const float* __restrict__ Whh_fw,
                         const float* __restrict__ bih_fw, const float* __restrict__ bhh_fw,
                         const float* __restrict__ Wih_bw, const float* __restrict__ Whh_bw,
                         const float* __restrict__ bih_bw, const float* __restrict__ bhh_bw,
                         u16* __restrict__ wsu)
{
  const int bid = blockIdx.x, tid = threadIdx.x;
  if (bid < PREP_PACK_BLKS) {
    // -------- Whh pack (bf16 hi only) --------
    int idx = bid*256 + tid;                  // 2*PK_HHD elements
    int d = idx / PK_HHD;
    int e = idx - d*PK_HHD;
    const float* Whh = d ? Whh_bw : Whh_fw;
    int jj   = e & 7;
    int lane = (e >> 3) & 63;
    int kc   = (e >> 9) & 7;
    int gnt  = e >> 12;                       // nt*3+g, < 48
    int g = gnt % 3, nt = gnt / 3;
    int row = g*256 + nt*16 + (lane & 15);
    int k   = kc*32 + ((lane >> 4) << 3) + jj;
    wsu[idx] = f2bf(Whh[row*HHH + k]);
  } else if (bid < PREP_PACK_BLKS + PREP_XP_BLKS) {
    // -------- XP table, tiled: block = (8 chars x dir), embed rows in LDS --------
    const int b    = bid - PREP_PACK_BLKS;
    const int dirb = b & 1;
    const int c0   = (b >> 1) * XP_NCH;
    const float* Wih = dirb ? Wih_bw : Wih_fw;
    u16* xpo = wsu + XP_OFF_U16 + (size_t)dirb*XPD;

    __shared__ float sh_E[XP_NCH][EE];        // 4 KB
    for (int i = tid; i < XP_NCH*EE; i += 256) {
      int c = c0 + i/EE;
      sh_E[0][i] = (c < VOCABN) ? emb[(size_t)c*EE + (i & (EE-1))] : 0.0f;
    }
    __syncthreads();

    #pragma unroll 1
    for (int q = 0; q < 3; ++q) {             // gate channel g = q*256 + tid
      const int g = q*256 + tid;
      const float* W = Wih + (size_t)g*EE;
      float acc[XP_NCH];
      #pragma unroll
      for (int c = 0; c < XP_NCH; ++c) acc[c] = 0.0f;
      #pragma unroll 2
      for (int k = 0; k < EE; k += 4) {
        float4 wv = *(const float4*)(W + k);
        #pragma unroll
        for (int c = 0; c < XP_NCH; ++c) {
          float4 ev = *(const float4*)(&sh_E[c][k]);
          acc[c] = fmaf(ev.w, wv.w, fmaf(ev.z, wv.z, fmaf(ev.y, wv.y, fmaf(ev.x, wv.x, acc[c]))));
        }
      }
      #pragma unroll
      for (int c = 0; c < XP_NCH; ++c) {
        int ci = c0 + c;
        if (ci < VOCABN) xpo[(size_t)ci*768 + g] = f2bf(acc[c]);
      }
    }
  } else {
    // -------- biases (one block handles all 2048, 8 per thread) --------
    #pragma unroll
    for (int rep = 0; rep < 8; ++rep) {
      int i = rep*256 + tid;
      int d = i >> 10, o = i & 1023;
      const float* bih = d ? bih_bw : bih_fw;
      const float* bhh = d ? bhh_bw : bhh_fw;
      float v;
      if (o < 512)      v = bih[o] + bhh[o];
      else if (o < 768) v = bih[o - 512 + 512];   // bih_n
      else              v = bhh[o - 768 + 512];   // bhh_n
      ((float*)(wsu + BIAS_OFF_U16))[d*1024 + o] = v;
    }
  }
}

// ==== R3 structure, spill-free:
//  - __launch_bounds__(1024, 4): LDS already caps at 1 block/CU (16 waves =
//    4 waves/EU), so declare it -> VGPR budget 64 -> 128. R3's 468 MB WRITE /
//    +660 MB FETCH were scratch spills of registers held across the MFMA phase.
//  - xp prefetch holds ZERO VGPRs: global_load_lds (16B/lane) into gate-plane
//    LDS buffers. Wave-uniform dest: lanes 0..31 fill word 2w's 512B plane row,
//    lanes 32..63 word 2w+1's (contiguous 1024B per wave). +32B pad per
//    wave-pair makes epilogue u16 reads 2-way (free). Loads issued after S0,
//    drained by the compiler's pre-barrier vmcnt(0) at S2 -> full MFMA phase
//    covers L2/L3 latency. ds_write phase deleted.
//  - register h epilogue, ballot step-masks, transposed chars, nt single-touch
//    loads/stores kept from R1/R3.
__global__ __launch_bounds__(1024, 4)
void gru_mfma(const int* __restrict__ chars, const int* __restrict__ chars_mask,
              const int* __restrict__ data_mask, const u16* __restrict__ wsu,
              float* __restrict__ out)
{
  const int dir   = blockIdx.x & 1;           // XCD parity: one dir per XCD
  const int word0 = (blockIdx.x >> 1) * MMW;
  const int j     = threadIdx.x;              // 0..1023 = 16 waves (4 per SIMD)
  const int wave  = j >> 6, lane = j & 63;
  const int quad  = lane >> 4, l15 = lane & 15;

  const bf16x8* pHH  = (const bf16x8*)(wsu + (size_t)dir*PK_HHD);
  const u16*    xpt  = wsu + XP_OFF_U16 + (size_t)dir*XPD;
  const float*  bias = (const float*)(wsu + BIAS_OFF_U16) + dir*1024;

  // this wave owns gate-tile nt == wave (16 output channels)
  const bf16x8* bHH = pHH + (size_t)(wave*3)*8*64 + lane;

  __shared__ __align__(16) u16 sh_hhi[MMW][HS];       // bf16 hi of h (16.9 KB)
  __shared__ __align__(16) u16 sh_hlo[MMW][HS];       // bf16 lo of h (16.9 KB)
  __shared__ __align__(16) u16 sh_xpg[2][3][16][XPW]; // xp gate planes, dbuf (99 KB)
  __shared__ __align__(16) int sh_cit[CC][MMW];       // chars, transposed (4 KB)
  __shared__ u32 sh_mb[MMW];                          // per-word step-mask bits

  const int sw = j >> 5, sp = j & 31;       // xp-staging: word (32), 16B part (32)

  // ---- one-time staging ----
  {
    const int w = sw, c = sp;
    sh_cit[c][w] = __builtin_nontemporal_load(&chars[(word0 + w)*CC + c]);
    int mv = __builtin_nontemporal_load(&chars_mask[(word0 + w)*CC + c]);
    u64 bal = __ballot(mv != 0);            // lanes 0..31 -> word 2*wave, 32..63 -> 2*wave+1
    if (lane == 0) {
      sh_mb[2*wave]     = (u32)bal;
      sh_mb[2*wave + 1] = (u32)(bal >> 32);
    }
  }
  for (int i = j; i < MMW*HS/2; i += 1024) { ((float*)sh_hhi)[i] = 0.0f; ((float*)sh_hlo)[i] = 0.0f; }
  // prologue: stage xp buf0 for the first char (chars read directly; sh_cit not synced yet)
  {
    const int t0 = dir ? (CC - 1) : 0;
    int ci0 = __builtin_nontemporal_load(&chars[(word0 + sw)*CC + t0]);
    const u16* gs = xpt + (size_t)ci0*768 + sp*8;
    #pragma unroll
    for (int l = 0; l < 3; ++l)
      gload_lds16(gs + l*256, &sh_xpg[0][l][wave][0]);
  }
  __syncthreads();

  const int ch = wave*16 + l15;             // this lane's output channel
  const float bR  = bias[ch],        bZ  = bias[256 + ch];
  const float bXN = bias[512 + ch],  bHN = bias[768 + ch];

  // per-lane owned words: word = m*16 + quad*4 + r
  u32 mb[2][4];
  float hreg[2][4];
  #pragma unroll
  for (int m = 0; m < 2; ++m)
    #pragma unroll
    for (int r = 0; r < 4; ++r) {
      mb[m][r] = sh_mb[m*16 + quad*4 + r];
      hreg[m][r] = 0.0f;
    }

  // 8 HH batches per step (kc 0..7), 3 frags each. FOUR buffer slots so the
  // rotation is step-aligned (8 % 4 == 0; 3 slots permuted kc across steps).
  bf16x8 buf[4][3];
  auto load_batch = [&](int kc, bf16x8 dst[3]) {
    #pragma unroll
    for (int g = 0; g < 3; ++g) dst[g] = bHH[(g*8 + kc)*64];
  };
  load_batch(0, buf[0]);
  load_batch(1, buf[1]);
  load_batch(2, buf[2]);

  #pragma unroll 1
  for (int s = 0; s < CC; ++s) {
    __syncthreads();                                   // S0: h writes + prev-step xp reads done

    // ---- async-issue next step's xp rows into the other plane buffer ----
    const bool hasn = (s + 1 < CC);
    if (hasn) {
      int tn = dir ? (CC - 2 - s) : (s + 1);
      int ci = sh_cit[tn][sw];
      const u16* gs = xpt + (size_t)ci*768 + sp*8;
      u16* lb = &sh_xpg[(s+1)&1][0][wave][0];
      gload_lds16(gs,       lb);
      gload_lds16(gs + 256, lb + XPL);
      gload_lds16(gs + 512, lb + 2*XPL);
    }

    // acc[0]=r, acc[1]=z, acc[2]=hn ; [m-tile]  (24 regs)
    f32x4 acc[3][2];
    #pragma unroll
    for (int m = 0; m < 2; ++m) {
      acc[0][m] = (f32x4){bR,bR,bR,bR};
      acc[1][m] = (f32x4){bZ,bZ,bZ,bZ};
      acc[2][m] = (f32x4){bHN,bHN,bHN,bHN};
    }

    // r,z gates: h_hi only (bounded, non-compounding error). n gate: exact hi+lo.
    auto mfma_batch = [&](int kc, bf16x8 src[3]) {
      #pragma unroll
      for (int m = 0; m < 2; ++m) {
        bf16x8 ah = *(const bf16x8*)&sh_hhi[m*16 + l15][kc*32 + quad*8];
        bf16x8 al = *(const bf16x8*)&sh_hlo[m*16 + l15][kc*32 + quad*8];
        acc[0][m] = __builtin_amdgcn_mfma_f32_16x16x32_bf16(ah, src[0], acc[0][m], 0,0,0);
        acc[1][m] = __builtin_amdgcn_mfma_f32_16x16x32_bf16(ah, src[1], acc[1][m], 0,0,0);
        acc[2][m] = __builtin_amdgcn_mfma_f32_16x16x32_bf16(ah, src[2], acc[2][m], 0,0,0);
        acc[2][m] = __builtin_amdgcn_mfma_f32_16x16x32_bf16(al, src[2], acc[2][m], 0,0,0);
      }
    };

    #pragma unroll
    for (int b = 0; b < 8; ++b) {
      mfma_batch(b, buf[b & 3]);
      load_batch((b + 3) & 7, buf[(b + 3) & 3]);       // b>=5 pre-issues next step's 0,1,2
    }

    __syncthreads();                                   // S2: h frag reads done; xp loads drained

    // ---- gate math + h update (lane owns (word, ch); h_old in regs) ----
    const int t = dir ? (CC - 1 - s) : s;
    const u16* xb = &sh_xpg[s & 1][0][0][0];
    #pragma unroll
    for (int m = 0; m < 2; ++m)
      #pragma unroll
      for (int r = 0; r < 4; ++r) {
        const int word = m*16 + quad*4 + r;
        const int xi = (word >> 1)*XPW + (word & 1)*256 + ch;
        float xr = bf2f(xb[xi]);
        float xz = bf2f(xb[xi + XPL]);
        float xn = bf2f(xb[xi + 2*XPL]);
        float rr = sigmoid_f(acc[0][m][r] + xr);
        float zz = sigmoid_f(acc[1][m][r] + xz);
        float nn = tanh_f(fmaf(rr, acc[2][m][r], bXN + xn));
        float hold = hreg[m][r];
        float hnew = fmaf(zz, hold - nn, nn);                  // (1-z)*n + z*h
        float cmf  = (float)((mb[m][r] >> t) & 1u);
        float hm   = fmaf(cmf, hnew - hold, hold);             // mask freeze
        hreg[m][r] = hm;
        u16 hi = f2bf(hm);
        sh_hhi[word][ch] = hi;
        sh_hlo[word][ch] = f2bf(hm - bf2f(hi));
      }
  }

  // ---- output straight from registers (owner mapping), nt stores ----
  #pragma unroll
  for (int m = 0; m < 2; ++m)
    #pragma unroll
    for (int r = 0; r < 4; ++r) {
      const int word = m*16 + quad*4 + r;
      float dm = (float)__builtin_nontemporal_load(&data_mask[word0 + word]);
      __builtin_nontemporal_store(hreg[m][r] * dm,
                                  &out[(size_t)(word0 + word)*(2*HHH) + dir*HHH + ch]);
    }
}

extern "C" void kernel_launch(void* const* d_in, const int* in_sizes, int n_in,
                              void* d_out, int out_size, void* d_ws, size_t ws_size,
                              hipStream_t stream) {
  const int*   chars      = (const int*)d_in[0];
  const int*   chars_mask = (const int*)d_in[1];
  const int*   data_mask  = (const int*)d_in[2];
  const float* embed      = (const float*)d_in[3];
  const float* Wih_fw     = (const float*)d_in[4];
  const float* Whh_fw     = (const float*)d_in[5];
  const float* bih_fw     = (const float*)d_in[6];
  const float* bhh_fw     = (const float*)d_in[7];
  const float* Wih_bw     = (const float*)d_in[8];
  const float* Whh_bw     = (const float*)d_in[9];
  const float* bih_bw     = (const float*)d_in[10];
  const float* bhh_bw     = (const float*)d_in[11];
  u16* wsu = (u16*)d_ws;

  prep_all<<<PREP_BLKS, 256, 0, stream>>>(embed, Wih_fw, Whh_fw, bih_fw, bhh_fw,
                                          Wih_bw, Whh_bw, bih_bw, bhh_bw, wsu);

  // 256 blocks: (word-group, dir) packed so dir == blockIdx&1 (XCD parity)
  gru_mfma<<<(NWORDS/MMW)*2, 1024, 0, stream>>>(chars, chars_mask, data_mask, wsu, (float*)d_out);
}